// Round 1
// baseline (1134.108 us; speedup 1.0000x reference)
//
#include <hip/hip_runtime.h>

#define NN 100000
#define EE 3200000
#define DD 256
#define CC 40

// Build CSR row_ptr from the sorted adj_row array.
// row_ptr[r] = first edge index with adj_row[e] >= r; row_ptr[NN] = EE.
__global__ __launch_bounds__(256) void k_row_ptr(const int* __restrict__ adj_row,
                                                 int* __restrict__ row_ptr) {
    int e = blockIdx.x * 256 + threadIdx.x;
    if (e >= EE) return;
    int r = adj_row[e];
    int prev = (e == 0) ? -1 : adj_row[e - 1];
    for (int rr = prev + 1; rr <= r; ++rr) row_ptr[rr] = e;
    if (e == EE - 1) {
        for (int rr = r + 1; rr <= NN; ++rr) row_ptr[rr] = EE;
    }
}

// Fused: h_row = relu(sum_e vals[e]*x[col[e],:]) * drop_mask_row * 2
//        z_row[c] = h_row . W[c,:] + b[c]
// One block (256 threads) per output row; thread d owns feature dim d.
__global__ __launch_bounds__(256) void k_spmm1_lin(
    const float* __restrict__ x, const float* __restrict__ adj_vals,
    const int* __restrict__ adj_col, const int* __restrict__ row_ptr,
    const float* __restrict__ drop_mask, const float* __restrict__ W,
    const float* __restrict__ b, float* __restrict__ z)
{
    int row = blockIdx.x;
    int d = threadIdx.x;
    int e0 = row_ptr[row], e1 = row_ptr[row + 1];
    float acc = 0.f;
    for (int e = e0; e < e1; ++e) {
        float v = adj_vals[e];   // wave-uniform -> scalar load
        int c = adj_col[e];      // wave-uniform -> scalar load
        acc = fmaf(v, x[(size_t)c * DD + d], acc);  // coalesced 1KB/row
    }
    float h = fmaxf(acc, 0.f) * drop_mask[(size_t)row * DD + d] * 2.0f;

    __shared__ float hs[DD];
    hs[d] = h;
    __syncthreads();

    // Linear 256->40: 4 threads per class, stride-4 partials (bank-conflict free:
    // the 4 j-lanes hit 4 distinct banks; same-j lanes across classes broadcast).
    if (d < CC * 4) {
        int c = d >> 2, j = d & 3;
        const float* wr = W + c * DD;
        float p = 0.f;
#pragma unroll 8
        for (int k = 0; k < DD / 4; ++k) {
            int idx = 4 * k + j;
            p = fmaf(hs[idx], wr[idx], p);
        }
        p += __shfl_down(p, 2);
        p += __shfl_down(p, 1);
        if (j == 0) z[(size_t)row * CC + c] = p + b[c];
    }
}

// out = SpMM(z), z is [NN, 40]. One wave per row, lane c (<40) owns class c.
__global__ __launch_bounds__(256) void k_spmm2(
    const float* __restrict__ z, const float* __restrict__ adj_vals,
    const int* __restrict__ adj_col, const int* __restrict__ row_ptr,
    float* __restrict__ out)
{
    int wave = threadIdx.x >> 6;
    int lane = threadIdx.x & 63;
    int row = blockIdx.x * 4 + wave;
    if (row >= NN) return;
    int e0 = row_ptr[row], e1 = row_ptr[row + 1];
    float acc = 0.f;
    for (int e = e0; e < e1; ++e) {
        float v = adj_vals[e];
        int c = adj_col[e];
        if (lane < CC) acc = fmaf(v, z[(size_t)c * CC + lane], acc);
    }
    if (lane < CC) out[(size_t)row * CC + lane] = acc;
}

extern "C" void kernel_launch(void* const* d_in, const int* in_sizes, int n_in,
                              void* d_out, int out_size, void* d_ws, size_t ws_size,
                              hipStream_t stream) {
    const float* x         = (const float*)d_in[0];
    const float* adj_vals  = (const float*)d_in[1];
    const float* W         = (const float*)d_in[2];
    const float* b         = (const float*)d_in[3];
    const float* drop_mask = (const float*)d_in[4];
    const int*   adj_row   = (const int*)d_in[5];
    const int*   adj_col   = (const int*)d_in[6];
    float* out = (float*)d_out;

    // Workspace layout: row_ptr [(NN+1) ints] | z [NN*CC floats]
    int* row_ptr = (int*)d_ws;
    size_t rp_bytes = ((size_t)(NN + 1) * 4 + 255) & ~(size_t)255;
    float* z = (float*)((char*)d_ws + rp_bytes);

    hipLaunchKernelGGL(k_row_ptr, dim3((EE + 255) / 256), dim3(256), 0, stream,
                       adj_row, row_ptr);
    hipLaunchKernelGGL(k_spmm1_lin, dim3(NN), dim3(256), 0, stream,
                       x, adj_vals, adj_col, row_ptr, drop_mask, W, b, z);
    hipLaunchKernelGGL(k_spmm2, dim3((NN + 3) / 4), dim3(256), 0, stream,
                       z, adj_vals, adj_col, row_ptr, out);
}

// Round 2
// 725.054 us; speedup vs baseline: 1.5642x; 1.5642x over previous
//
#include <hip/hip_runtime.h>

#define NN 100000
#define EE 3200000
#define DD 256
#define CC 40

// Build CSR row_ptr from the sorted adj_row array.
__global__ __launch_bounds__(256) void k_row_ptr(const int* __restrict__ adj_row,
                                                 int* __restrict__ row_ptr) {
    int e = blockIdx.x * 256 + threadIdx.x;
    if (e >= EE) return;
    int r = adj_row[e];
    int prev = (e == 0) ? -1 : adj_row[e - 1];
    for (int rr = prev + 1; rr <= r; ++rr) row_ptr[rr] = e;
    if (e == EE - 1) {
        for (int rr = r + 1; rr <= NN; ++rr) row_ptr[rr] = EE;
    }
}

// Fused SpMM1 + relu + dropout + Linear(256->40).
// One WAVE per row; lane l owns dims [4l..4l+3] as float4.
// Edge loop unrolled x8: metadata batched via scalar loads, then 8 independent
// 16B/lane gathers in flight before the fmas (latency hiding).
__global__ __launch_bounds__(256) void k_spmm1_lin(
    const float* __restrict__ x, const float* __restrict__ adj_vals,
    const int* __restrict__ adj_col, const int* __restrict__ row_ptr,
    const float* __restrict__ drop_mask, const float* __restrict__ W,
    const float* __restrict__ b, float* __restrict__ z)
{
    int wave = threadIdx.x >> 6;
    int lane = threadIdx.x & 63;
    int row = blockIdx.x * 4 + wave;   // NN % 4 == 0, grid covers exactly

    const float4* x4 = (const float4*)x;
    int e0 = __builtin_amdgcn_readfirstlane(row_ptr[row]);
    int e1 = __builtin_amdgcn_readfirstlane(row_ptr[row + 1]);

    float4 acc = {0.f, 0.f, 0.f, 0.f};
    int e = e0;
    for (; e + 8 <= e1; e += 8) {
        float vv[8]; int cc[8];
#pragma unroll
        for (int u = 0; u < 8; ++u) {
            vv[u] = adj_vals[e + u];
            cc[u] = adj_col[e + u];
        }
        float4 xa[8];
#pragma unroll
        for (int u = 0; u < 8; ++u)
            xa[u] = x4[(size_t)cc[u] * (DD / 4) + lane];
#pragma unroll
        for (int u = 0; u < 8; ++u) {
            acc.x = fmaf(vv[u], xa[u].x, acc.x);
            acc.y = fmaf(vv[u], xa[u].y, acc.y);
            acc.z = fmaf(vv[u], xa[u].z, acc.z);
            acc.w = fmaf(vv[u], xa[u].w, acc.w);
        }
    }
    for (; e < e1; ++e) {
        float v = adj_vals[e];
        int c = adj_col[e];
        float4 xa = x4[(size_t)c * (DD / 4) + lane];
        acc.x = fmaf(v, xa.x, acc.x);
        acc.y = fmaf(v, xa.y, acc.y);
        acc.z = fmaf(v, xa.z, acc.z);
        acc.w = fmaf(v, xa.w, acc.w);
    }

    // relu + dropout (keep=0.5 -> scale 2)
    float4 mm = ((const float4*)drop_mask)[(size_t)row * (DD / 4) + lane];
    float4 h;
    h.x = fmaxf(acc.x, 0.f) * mm.x * 2.f;
    h.y = fmaxf(acc.y, 0.f) * mm.y * 2.f;
    h.z = fmaxf(acc.z, 0.f) * mm.z * 2.f;
    h.w = fmaxf(acc.w, 0.f) * mm.w * 2.f;

    // Stage h row in this wave's LDS slice (no cross-wave sync needed).
    __shared__ float hs[4][DD];
    ((float4*)hs[wave])[lane] = h;

    // Linear 256->40: lane c (<40) computes the full dot; LDS reads are
    // same-address broadcasts (conflict-free), W rows are L1-resident (40KB).
    if (lane < CC) {
        const float4* wr = (const float4*)(W + (size_t)lane * DD);
        const float4* hv = (const float4*)hs[wave];
        float4 p = {0.f, 0.f, 0.f, 0.f};
#pragma unroll 8
        for (int k = 0; k < DD / 4; ++k) {
            float4 wk = wr[k];
            float4 hk = hv[k];
            p.x = fmaf(hk.x, wk.x, p.x);
            p.y = fmaf(hk.y, wk.y, p.y);
            p.z = fmaf(hk.z, wk.z, p.z);
            p.w = fmaf(hk.w, wk.w, p.w);
        }
        z[(size_t)row * CC + lane] = p.x + p.y + p.z + p.w + b[lane];
    }
}

// out = SpMM(z), z is [NN, 40]. One wave per row, lane c owns class c
// (lanes 40..63 clamped to 39 to avoid exec-mask churn; store is masked).
__global__ __launch_bounds__(256) void k_spmm2(
    const float* __restrict__ z, const float* __restrict__ adj_vals,
    const int* __restrict__ adj_col, const int* __restrict__ row_ptr,
    float* __restrict__ out)
{
    int wave = threadIdx.x >> 6;
    int lane = threadIdx.x & 63;
    int row = blockIdx.x * 4 + wave;
    int cl = lane < CC ? lane : CC - 1;

    int e0 = __builtin_amdgcn_readfirstlane(row_ptr[row]);
    int e1 = __builtin_amdgcn_readfirstlane(row_ptr[row + 1]);

    float acc = 0.f;
    int e = e0;
    for (; e + 8 <= e1; e += 8) {
        float vv[8]; int cc[8];
#pragma unroll
        for (int u = 0; u < 8; ++u) {
            vv[u] = adj_vals[e + u];
            cc[u] = adj_col[e + u];
        }
        float za[8];
#pragma unroll
        for (int u = 0; u < 8; ++u)
            za[u] = z[(size_t)cc[u] * CC + cl];
#pragma unroll
        for (int u = 0; u < 8; ++u)
            acc = fmaf(vv[u], za[u], acc);
    }
    for (; e < e1; ++e) {
        float v = adj_vals[e];
        int c = adj_col[e];
        acc = fmaf(v, z[(size_t)c * CC + cl], acc);
    }
    if (lane < CC) out[(size_t)row * CC + lane] = acc;
}

extern "C" void kernel_launch(void* const* d_in, const int* in_sizes, int n_in,
                              void* d_out, int out_size, void* d_ws, size_t ws_size,
                              hipStream_t stream) {
    const float* x         = (const float*)d_in[0];
    const float* adj_vals  = (const float*)d_in[1];
    const float* W         = (const float*)d_in[2];
    const float* b         = (const float*)d_in[3];
    const float* drop_mask = (const float*)d_in[4];
    const int*   adj_row   = (const int*)d_in[5];
    const int*   adj_col   = (const int*)d_in[6];
    float* out = (float*)d_out;

    int* row_ptr = (int*)d_ws;
    size_t rp_bytes = ((size_t)(NN + 1) * 4 + 255) & ~(size_t)255;
    float* z = (float*)((char*)d_ws + rp_bytes);

    hipLaunchKernelGGL(k_row_ptr, dim3((EE + 255) / 256), dim3(256), 0, stream,
                       adj_row, row_ptr);
    hipLaunchKernelGGL(k_spmm1_lin, dim3(NN / 4), dim3(256), 0, stream,
                       x, adj_vals, adj_col, row_ptr, drop_mask, W, b, z);
    hipLaunchKernelGGL(k_spmm2, dim3(NN / 4), dim3(256), 0, stream,
                       z, adj_vals, adj_col, row_ptr, out);
}